// Round 1
// baseline (3229.254 us; speedup 1.0000x reference)
//
#include <hip/hip_runtime.h>
#include <math.h>

#define MDIM 1024
#define TSEQ 2048
#define NSOL 5
#define DED  64
#define NBLK 3
#define KITER 10
#define XLD  1088   // X leading dim: 1024 sp cols + 64 demb cols

__device__ __forceinline__ float gelu_f(float x){
  return 0.5f * x * (1.0f + erff(x * 0.70710678118654752440f));
}
__device__ __forceinline__ float sigmoid_f(float x){ return 1.0f/(1.0f+expf(-x)); }
__device__ __forceinline__ float softplus_f(float x){ return fmaxf(x,0.0f) + log1pf(expf(-fabsf(x))); }

// ---------------- init speculative state ----------------
__global__ void k_init(float* prevg, int* dlist, int* dcnt){
  int i = blockIdx.x*blockDim.x + threadIdx.x;
  if (i < TSEQ){ prevg[i] = (i==0)? -1.0f : 1.0f; dlist[i] = i; }
  if (i == 0) *dcnt = TSEQ;
}

// ---------------- P[s][j] = solvent_vecs[s] @ sp_proj_w block s ----------------
__global__ void k_solvP(const float* __restrict__ sv, const float* __restrict__ W,
                        float* __restrict__ P){
  int s = blockIdx.y;
  int j = blockIdx.x*256 + threadIdx.x;
  const float* w = W + (size_t)s*MDIM*MDIM + j;
  const float* v = sv + s*MDIM;
  float acc = 0.f;
  for (int k=0;k<MDIM;k++) acc = fmaf(v[k], w[(size_t)k*MDIM], acc);
  P[s*MDIM + j] = acc;
}

// ---------------- sp0[t][j] = gelu(sum_s ratios[t][s]*P[s][j] + b[j]) ----------------
__global__ void k_sp0(const float* __restrict__ ratios, const float* __restrict__ P,
                      const float* __restrict__ bias, float* __restrict__ X){
  int t = blockIdx.y;
  int j = blockIdx.x*256 + threadIdx.x;
  const float* r = ratios + t*NSOL;
  float acc = bias[j];
  #pragma unroll
  for (int s=0;s<NSOL;s++) acc = fmaf(r[s], P[s*MDIM+j], acc);
  X[(size_t)t*XLD + j] = gelu_f(acc);
}

// ---------------- demb[t][e] = gelu(desc[t] @ desc_w + desc_b) ----------------
__global__ void k_demb(const float* __restrict__ desc, const float* __restrict__ dw,
                       const float* __restrict__ db, float* __restrict__ X){
  int t = blockIdx.x; int e = threadIdx.x;
  const float* d = desc + t*6;
  float acc = db[e];
  #pragma unroll
  for (int c=0;c<6;c++) acc = fmaf(d[c], dw[c*DED+e], acc);
  X[(size_t)t*XLD + MDIM + e] = gelu_f(acc);
}

// ---------------- molpart[j] = mol_vec @ bh_proj_w[0:1024] + bh_proj_b ----------------
__global__ void k_molpart(const float* __restrict__ mol, const float* __restrict__ bhw,
                          const float* __restrict__ bhb, float* __restrict__ mp){
  int j = blockIdx.x*256 + threadIdx.x;
  float acc = bhb[j];
  for (int k=0;k<MDIM;k++) acc = fmaf(mol[k], bhw[(size_t)k*MDIM + j], acc);
  mp[j] = acc;
}

// ---------------- generic fp32 GEMM: C[t][j] = epi(sum_k A[t][k]*B[k][j]) ----------------
// B row-major with ldb = 1024 (all weight matrices). M=2048 rows, N=1024 cols.
template<bool GELU, bool RES>
__global__ __launch_bounds__(256) void k_gemm(
    const float* __restrict__ A, int lda,
    const float* __restrict__ B,
    float* __restrict__ C, int ldc,
    int K,
    const float* __restrict__ bias,
    const float* __restrict__ Rz, int ldr)
{
  __shared__ float As[64][17];
  __shared__ float Bs[16][65];
  int tid = threadIdx.x;
  int row0 = blockIdx.y*64, col0 = blockIdx.x*64;
  int ty = tid>>4, tx = tid&15;
  float acc[4][4] = {};
  int am = tid>>2, ak = (tid&3)*4;
  int bj = tid&63, bk0 = tid>>6;
  for (int k0=0;k0<K;k0+=16){
    const float4 av = *(const float4*)(A + (size_t)(row0+am)*lda + k0 + ak);
    As[am][ak+0]=av.x; As[am][ak+1]=av.y; As[am][ak+2]=av.z; As[am][ak+3]=av.w;
    #pragma unroll
    for (int r=0;r<4;r++){
      int k = bk0 + r*4;
      Bs[k][bj] = B[(size_t)(k0+k)*MDIM + col0 + bj];
    }
    __syncthreads();
    #pragma unroll
    for (int kk=0;kk<16;kk++){
      float a[4], b[4];
      #pragma unroll
      for (int i=0;i<4;i++) a[i]=As[ty+16*i][kk];
      #pragma unroll
      for (int j=0;j<4;j++) b[j]=Bs[kk][tx+16*j];
      #pragma unroll
      for (int i=0;i<4;i++)
        #pragma unroll
        for (int j=0;j<4;j++)
          acc[i][j] = fmaf(a[i], b[j], acc[i][j]);
    }
    __syncthreads();
  }
  #pragma unroll
  for (int i=0;i<4;i++){
    int r = row0 + ty + 16*i;
    #pragma unroll
    for (int j=0;j<4;j++){
      int c = col0 + tx + 16*j;
      float v = acc[i][j] + bias[c];
      if (RES) v += Rz[(size_t)r*ldr + c];
      if (GELU) v = gelu_f(v);
      C[(size_t)r*ldc + c] = v;
    }
  }
}

// ---------------- batched LayerNorm: Xo[t] = g*(Y[t]-m)*rsqrt(v+eps)+b ----------------
__global__ __launch_bounds__(256) void k_ln(const float* __restrict__ Y, int ldy,
    float* __restrict__ Xo, int ldx,
    const float* __restrict__ g, const float* __restrict__ b)
{
  int t = blockIdx.x;
  __shared__ float red[16];
  float y[4]; float s=0.f, s2=0.f;
  #pragma unroll
  for (int q=0;q<4;q++){
    y[q] = Y[(size_t)t*ldy + threadIdx.x + 256*q];
    s += y[q]; s2 += y[q]*y[q];
  }
  for (int o=32;o>0;o>>=1){ s += __shfl_down(s,o); s2 += __shfl_down(s2,o); }
  int wid = threadIdx.x>>6, lane = threadIdx.x&63;
  if (lane==0){ red[wid]=s; red[wid+8]=s2; }
  __syncthreads();
  if (threadIdx.x==0){
    float a=0.f,c=0.f;
    for (int w=0;w<4;w++){ a+=red[w]; c+=red[w+8]; }
    red[0]=a; red[8]=c;
  }
  __syncthreads();
  float mean = red[0]*(1.0f/MDIM);
  float var  = red[8]*(1.0f/MDIM) - mean*mean;
  float rs = rsqrtf(var + 1e-5f);
  #pragma unroll
  for (int q=0;q<4;q++){
    int j = threadIdx.x + 256*q;
    Xo[(size_t)t*ldx + j] = g[j]*(y[q]-mean)*rs + b[j];
  }
}

// ---------------- per-row full beta-head (dirty rows only) ----------------
__global__ __launch_bounds__(1024) void k_head_row(
    const float* __restrict__ ZP, const float* __restrict__ wlast,
    const float* __restrict__ fc1w, const float* __restrict__ fc1b,
    const float* __restrict__ fc2w, const float* __restrict__ fc2b,
    const float* __restrict__ lng,  const float* __restrict__ lnb,
    const float* __restrict__ muw,  const float* __restrict__ mub,
    const float* __restrict__ phiw, const float* __restrict__ phib,
    const float* __restrict__ prevg,
    const int* __restrict__ dlist, const int* __restrict__ dcnt,
    float* __restrict__ muA, float* __restrict__ phiA)
{
  if ((int)blockIdx.x >= *dcnt) return;
  int t = dlist[blockIdx.x];
  __shared__ float zs[MDIM];
  __shared__ float hs[MDIM];
  __shared__ float red[32];
  int j = threadIdx.x;
  int wid = j>>6, lane = j&63;
  float prev = prevg[t];
  zs[j] = gelu_f(ZP[(size_t)t*MDIM + j] + prev*wlast[j]);
  __syncthreads();
  for (int blk=0; blk<NBLK; blk++){
    const float* W1 = fc1w + (size_t)blk*MDIM*MDIM;
    const float* W2 = fc2w + (size_t)blk*MDIM*MDIM;
    float acc = fc1b[blk*MDIM + j];
    for (int k=0;k<MDIM;k++) acc = fmaf(zs[k], W1[(size_t)k*MDIM + j], acc);
    hs[j] = gelu_f(acc);
    __syncthreads();
    float y = fc2b[blk*MDIM + j];
    for (int k=0;k<MDIM;k++) y = fmaf(hs[k], W2[(size_t)k*MDIM + j], y);
    y += zs[j];
    float s = y, s2 = y*y;
    for (int o=32;o>0;o>>=1){ s+=__shfl_down(s,o); s2+=__shfl_down(s2,o); }
    if (lane==0){ red[wid]=s; red[wid+16]=s2; }
    __syncthreads();
    if (wid==0){
      float a = (lane<16)? red[lane] : 0.f;
      float c = (lane<16)? red[lane+16] : 0.f;
      for (int o=8;o>0;o>>=1){ a+=__shfl_down(a,o); c+=__shfl_down(c,o); }
      if (lane==0){ red[0]=a; red[16]=c; }
    }
    __syncthreads();
    float mean = red[0]*(1.0f/MDIM);
    float var  = red[16]*(1.0f/MDIM) - mean*mean;
    float rs = rsqrtf(var + 1e-5f);
    float zn = lng[blk*MDIM+j]*(y-mean)*rs + lnb[blk*MDIM+j];
    __syncthreads();
    zs[j] = zn;
    __syncthreads();
  }
  float sm = zs[j]*muw[j];
  float sp = zs[j]*phiw[j];
  for (int o=32;o>0;o>>=1){ sm+=__shfl_down(sm,o); sp+=__shfl_down(sp,o); }
  if (lane==0){ red[wid]=sm; red[wid+16]=sp; }
  __syncthreads();
  if (wid==0){
    float a = (lane<16)? red[lane] : 0.f;
    float c = (lane<16)? red[lane+16] : 0.f;
    for (int o=8;o>0;o>>=1){ a+=__shfl_down(a,o); c+=__shfl_down(c,o); }
    if (lane==0){
      muA[t]  = sigmoid_f(a + mub[0]);
      phiA[t] = softplus_f(c + phib[0]) + 2.0f;
    }
  }
}

// ---------------- segmented prefix-product scan + dirty detection + output ----------------
__global__ __launch_bounds__(1024) void k_scan(
    const float* __restrict__ muA, const float* __restrict__ phiA,
    const unsigned char* __restrict__ bmask,
    float* __restrict__ prevg, int* __restrict__ dlist, int* __restrict__ dcnt,
    float* __restrict__ out)
{
  __shared__ float v[2][TSEQ];
  __shared__ unsigned char f[2][TSEQ];
  __shared__ int cnt;
  int tid = threadIdx.x;
  if (tid==0) cnt = 0;
  for (int i=tid;i<TSEQ;i+=1024){
    v[0][i] = 1.0f - muA[i];
    f[0][i] = (i==0) || (bmask[i] != 0);
  }
  __syncthreads();
  int src=0;
  for (int off=1; off<TSEQ; off<<=1){
    int dst = src^1;
    for (int i=tid;i<TSEQ;i+=1024){
      float vv = v[src][i]; unsigned char ff = f[src][i];
      if (i>=off && !ff){ vv *= v[src][i-off]; ff = f[src][i-off]; }
      v[dst][i]=vv; f[dst][i]=ff;
    }
    __syncthreads();
    src = dst;
  }
  for (int i=tid;i<TSEQ;i+=1024){
    float rf = 1.0f - v[src][i];
    float prev = (i==0) ? -1.0f : (1.0f - v[src][i-1]);
    out[i]        = rf;
    out[TSEQ+i]   = muA[i];
    out[2*TSEQ+i] = phiA[i];
    float old = prevg[i];
    prevg[i] = prev;
    if (fabsf(prev - old) > 1e-6f){
      int pos = atomicAdd(&cnt, 1);
      dlist[pos] = i;
    }
  }
  __syncthreads();
  if (tid==0) *dcnt = cnt;
}

extern "C" void kernel_launch(void* const* d_in, const int* in_sizes, int n_in,
                              void* d_out, int out_size, void* d_ws, size_t ws_size,
                              hipStream_t stream) {
  const float* mol       = (const float*)d_in[0];
  const float* ratios    = (const float*)d_in[1];
  const float* desc      = (const float*)d_in[2];
  const float* svvec     = (const float*)d_in[3];
  const unsigned char* bmask = (const unsigned char*)d_in[4];
  const float* sp_proj_w = (const float*)d_in[5];
  const float* sp_proj_b = (const float*)d_in[6];
  const float* sp_fc1_w  = (const float*)d_in[7];
  const float* sp_fc1_b  = (const float*)d_in[8];
  const float* sp_fc2_w  = (const float*)d_in[9];
  const float* sp_fc2_b  = (const float*)d_in[10];
  const float* sp_ln_g   = (const float*)d_in[11];
  const float* sp_ln_b   = (const float*)d_in[12];
  const float* desc_w    = (const float*)d_in[13];
  const float* desc_b    = (const float*)d_in[14];
  const float* bh_proj_w = (const float*)d_in[15];
  const float* bh_proj_b = (const float*)d_in[16];
  const float* bh_fc1_w  = (const float*)d_in[17];
  const float* bh_fc1_b  = (const float*)d_in[18];
  const float* bh_fc2_w  = (const float*)d_in[19];
  const float* bh_fc2_b  = (const float*)d_in[20];
  const float* bh_ln_g   = (const float*)d_in[21];
  const float* bh_ln_b   = (const float*)d_in[22];
  const float* mu_w      = (const float*)d_in[23];
  const float* mu_b      = (const float*)d_in[24];
  const float* phi_w     = (const float*)d_in[25];
  const float* phi_b     = (const float*)d_in[26];
  float* out = (float*)d_out;

  char* p = (char*)d_ws;
  auto alloc = [&](size_t bytes)->char*{ char* r = p; p += (bytes + 255) & ~(size_t)255; return r; };
  float* X    = (float*)alloc((size_t)TSEQ*XLD*4);
  float* Hb   = (float*)alloc((size_t)TSEQ*MDIM*4);
  float* Yb   = (float*)alloc((size_t)TSEQ*MDIM*4);
  float* ZP   = (float*)alloc((size_t)TSEQ*MDIM*4);
  float* P    = (float*)alloc((size_t)NSOL*MDIM*4);
  float* mp   = (float*)alloc(MDIM*4);
  float* prevg= (float*)alloc(TSEQ*4);
  float* muA  = (float*)alloc(TSEQ*4);
  float* phiA = (float*)alloc(TSEQ*4);
  int*   dlist= (int*)alloc(TSEQ*4);
  int*   dcnt = (int*)alloc(256);

  k_init<<<dim3((TSEQ+255)/256),256,0,stream>>>(prevg, dlist, dcnt);
  k_solvP<<<dim3(4,NSOL),256,0,stream>>>(svvec, sp_proj_w, P);
  k_sp0<<<dim3(4,TSEQ),256,0,stream>>>(ratios, P, sp_proj_b, X);
  k_demb<<<dim3(TSEQ),64,0,stream>>>(desc, desc_w, desc_b, X);
  k_molpart<<<dim3(4),256,0,stream>>>(mol, bh_proj_w, bh_proj_b, mp);

  for (int i=0;i<NBLK;i++){
    k_gemm<true,false><<<dim3(16,32),256,0,stream>>>(X, XLD, sp_fc1_w+(size_t)i*MDIM*MDIM,
        Hb, MDIM, MDIM, sp_fc1_b+i*MDIM, nullptr, 0);
    k_gemm<false,true><<<dim3(16,32),256,0,stream>>>(Hb, MDIM, sp_fc2_w+(size_t)i*MDIM*MDIM,
        Yb, MDIM, MDIM, sp_fc2_b+i*MDIM, X, XLD);
    k_ln<<<dim3(TSEQ),256,0,stream>>>(Yb, MDIM, X, XLD, sp_ln_g+i*MDIM, sp_ln_b+i*MDIM);
  }
  // z_pre = X[:, 0:1088] @ bh_proj_w[1024:2112] + (mol part incl. bias)
  k_gemm<false,false><<<dim3(16,32),256,0,stream>>>(X, XLD, bh_proj_w+(size_t)MDIM*MDIM,
      ZP, MDIM, XLD, mp, nullptr, 0);

  const float* wlast = bh_proj_w + (size_t)2112*MDIM;
  for (int it=0; it<KITER; it++){
    k_head_row<<<dim3(TSEQ),1024,0,stream>>>(ZP, wlast, bh_fc1_w, bh_fc1_b, bh_fc2_w, bh_fc2_b,
        bh_ln_g, bh_ln_b, mu_w, mu_b, phi_w, phi_b, prevg, dlist, dcnt, muA, phiA);
    k_scan<<<dim3(1),1024,0,stream>>>(muA, phiA, bmask, prevg, dlist, dcnt, out);
  }
  (void)in_sizes; (void)n_in; (void)out_size; (void)ws_size;
}

// Round 2
// 961.312 us; speedup vs baseline: 3.3592x; 3.3592x over previous
//
#include <hip/hip_runtime.h>
#include <math.h>

#define MDIM 1024
#define TSEQ 2048
#define NSOL 5
#define DED  64
#define NBLK 3
#define KITER 7
#define XLDB 1088   // bf16 X leading dim: 1024 sp cols + 64 demb cols
#define LDP  72     // padded LDS stride (bf16 elems): 144B rows -> 2-way (free) b128 reads

typedef __bf16 bf16x8 __attribute__((ext_vector_type(8)));
typedef float  f32x4  __attribute__((ext_vector_type(4)));

__device__ __forceinline__ float gelu_f(float x){
  return 0.5f * x * (1.0f + erff(x * 0.70710678118654752440f));
}
__device__ __forceinline__ float sigmoid_f(float x){ return 1.0f/(1.0f+expf(-x)); }
__device__ __forceinline__ float softplus_f(float x){ return fmaxf(x,0.0f) + log1pf(expf(-fabsf(x))); }

// ---------------- init speculative state ----------------
__global__ void k_init(float* prevg, int* dlist, int* dcnt){
  int i = blockIdx.x*blockDim.x + threadIdx.x;
  if (i < TSEQ){ prevg[i] = (i==0)? -1.0f : 1.0f; dlist[i] = i; }
  if (i == 0) *dcnt = TSEQ;
}

// ---------------- convert fp32 [K][N] -> bf16 transposed [N][K], z-stacked ----------------
__global__ __launch_bounds__(256) void k_cvtT(const float* __restrict__ src,
                                              __bf16* __restrict__ dst, int K, int N){
  __shared__ float t[32][33];
  int z = blockIdx.z;
  const float* s = src + (size_t)z*K*N;
  __bf16* d = dst + (size_t)z*N*K;
  int k0 = blockIdx.y*32, n0 = blockIdx.x*32;
  int tx = threadIdx.x & 31, ty = threadIdx.x >> 5; // ty 0..7
  #pragma unroll
  for (int r=0;r<32;r+=8) t[ty+r][tx] = s[(size_t)(k0+ty+r)*N + n0+tx];
  __syncthreads();
  #pragma unroll
  for (int r=0;r<32;r+=8) d[(size_t)(n0+ty+r)*K + k0+tx] = (__bf16)t[tx][ty+r];
}

// ---------------- P[s][j] = solvent_vecs[s] @ sp_proj_w block s ----------------
__global__ void k_solvP(const float* __restrict__ sv, const float* __restrict__ W,
                        float* __restrict__ P){
  int s = blockIdx.y;
  int j = blockIdx.x*256 + threadIdx.x;
  const float* w = W + (size_t)s*MDIM*MDIM + j;
  const float* v = sv + s*MDIM;
  float acc = 0.f;
  for (int k=0;k<MDIM;k++) acc = fmaf(v[k], w[(size_t)k*MDIM], acc);
  P[s*MDIM + j] = acc;
}

// ---------------- sp0[t][j] = gelu(sum_s ratios[t][s]*P[s][j] + b[j]) -> X fp32 + Xb bf16 ----------------
__global__ void k_sp0(const float* __restrict__ ratios, const float* __restrict__ P,
                      const float* __restrict__ bias, float* __restrict__ X,
                      __bf16* __restrict__ Xb){
  int t = blockIdx.y;
  int j = blockIdx.x*256 + threadIdx.x;
  const float* r = ratios + t*NSOL;
  float acc = bias[j];
  #pragma unroll
  for (int s=0;s<NSOL;s++) acc = fmaf(r[s], P[s*MDIM+j], acc);
  float v = gelu_f(acc);
  X[(size_t)t*MDIM + j] = v;
  Xb[(size_t)t*XLDB + j] = (__bf16)v;
}

// ---------------- demb[t][e] = gelu(desc[t] @ desc_w + desc_b) -> Xb cols 1024.. ----------------
__global__ void k_demb(const float* __restrict__ desc, const float* __restrict__ dw,
                       const float* __restrict__ db, __bf16* __restrict__ Xb){
  int t = blockIdx.x; int e = threadIdx.x;
  const float* d = desc + t*6;
  float acc = db[e];
  #pragma unroll
  for (int c=0;c<6;c++) acc = fmaf(d[c], dw[c*DED+e], acc);
  Xb[(size_t)t*XLDB + MDIM + e] = (__bf16)gelu_f(acc);
}

// ---------------- molpart[j] = mol_vec @ bh_proj_w[0:1024] + bh_proj_b ----------------
__global__ void k_molpart(const float* __restrict__ mol, const float* __restrict__ bhw,
                          const float* __restrict__ bhb, float* __restrict__ mp){
  int j = blockIdx.x*256 + threadIdx.x;
  float acc = bhb[j];
  for (int k=0;k<MDIM;k++) acc = fmaf(mol[k], bhw[(size_t)k*MDIM + j], acc);
  mp[j] = acc;
}

// ---------------- bf16 MFMA GEMM: C[t][j] = epi(sum_k A[t][k]*Bt[j][k] + bias[j]) ----------------
// BM=128, BN=64, BK=64, 256 threads (4 waves 2x2, each 64x32 = 4x2 16x16 frags).
template<bool GELU, bool RES, bool OUTF, bool OUTB>
__global__ __launch_bounds__(256) void k_mfma_gemm(
    const __bf16* __restrict__ A, int lda, int K,
    const __bf16* __restrict__ Bt,           // [N][K] bf16
    const float* __restrict__ bias,          // [N] fp32
    const float* __restrict__ R, int ldr,    // fp32 residual
    float* __restrict__ Cf, int ldcf,
    __bf16* __restrict__ Cb, int ldcb)
{
  __shared__ __attribute__((aligned(16))) __bf16 As[128*LDP];
  __shared__ __attribute__((aligned(16))) __bf16 Bs[64*LDP];
  int tid = threadIdx.x;
  int wave = tid>>6, lane = tid&63;
  int row0 = blockIdx.y*128, col0 = blockIdx.x*64;
  int wr = (wave>>1)*64, wc = (wave&1)*32;
  int lr = lane&15, lk = (lane>>4)*8;
  f32x4 acc[4][2] = {};
  for (int k0=0;k0<K;k0+=64){
    __syncthreads();
    #pragma unroll
    for (int p=0;p<4;p++){               // A: 128x64 = 1024 16B-chunks
      int c = p*256 + tid;
      int r = c>>3, kc = (c&7)*8;
      *(bf16x8*)&As[r*LDP + kc] = *(const bf16x8*)&A[(size_t)(row0+r)*lda + k0 + kc];
    }
    #pragma unroll
    for (int p=0;p<2;p++){               // Bt: 64x64 = 512 chunks
      int c = p*256 + tid;
      int r = c>>3, kc = (c&7)*8;
      *(bf16x8*)&Bs[r*LDP + kc] = *(const bf16x8*)&Bt[(size_t)(col0+r)*K + k0 + kc];
    }
    __syncthreads();
    #pragma unroll
    for (int ks=0;ks<2;ks++){
      int kk = ks*32 + lk;
      bf16x8 af[4], bg[2];
      #pragma unroll
      for (int m=0;m<4;m++) af[m] = *(const bf16x8*)&As[(wr + m*16 + lr)*LDP + kk];
      #pragma unroll
      for (int n=0;n<2;n++) bg[n] = *(const bf16x8*)&Bs[(wc + n*16 + lr)*LDP + kk];
      #pragma unroll
      for (int m=0;m<4;m++)
        #pragma unroll
        for (int n=0;n<2;n++)
          acc[m][n] = __builtin_amdgcn_mfma_f32_16x16x32_bf16(af[m], bg[n], acc[m][n], 0,0,0);
    }
  }
  int rq = (lane>>4)*4;  // verified C/D layout: col = lane&15, row = (lane>>4)*4 + q
  #pragma unroll
  for (int m=0;m<4;m++){
    #pragma unroll
    for (int n=0;n<2;n++){
      int c = col0 + wc + n*16 + lr;
      float bv = bias[c];
      #pragma unroll
      for (int q=0;q<4;q++){
        int r = row0 + wr + m*16 + rq + q;
        float v = acc[m][n][q] + bv;
        if (RES)  v += R[(size_t)r*ldr + c];
        if (GELU) v = gelu_f(v);
        if (OUTF) Cf[(size_t)r*ldcf + c] = v;
        if (OUTB) Cb[(size_t)r*ldcb + c] = (__bf16)v;
      }
    }
  }
}

// ---------------- batched LayerNorm -> fp32 + bf16 outputs ----------------
__global__ __launch_bounds__(256) void k_ln(const float* __restrict__ Y, int ldy,
    float* __restrict__ Xo, int ldx, __bf16* __restrict__ Xb, int ldxb,
    const float* __restrict__ g, const float* __restrict__ b)
{
  int t = blockIdx.x;
  __shared__ float red[16];
  float y[4]; float s=0.f, s2=0.f;
  #pragma unroll
  for (int q=0;q<4;q++){
    y[q] = Y[(size_t)t*ldy + threadIdx.x + 256*q];
    s += y[q]; s2 += y[q]*y[q];
  }
  for (int o=32;o>0;o>>=1){ s += __shfl_down(s,o); s2 += __shfl_down(s2,o); }
  int wid = threadIdx.x>>6, lane = threadIdx.x&63;
  if (lane==0){ red[wid]=s; red[wid+8]=s2; }
  __syncthreads();
  if (threadIdx.x==0){
    float a=0.f,c=0.f;
    for (int w=0;w<4;w++){ a+=red[w]; c+=red[w+8]; }
    red[0]=a; red[8]=c;
  }
  __syncthreads();
  float mean = red[0]*(1.0f/MDIM);
  float var  = red[8]*(1.0f/MDIM) - mean*mean;
  float rs = rsqrtf(var + 1e-5f);
  #pragma unroll
  for (int q=0;q<4;q++){
    int j = threadIdx.x + 256*q;
    float v = g[j]*(y[q]-mean)*rs + b[j];
    Xo[(size_t)t*ldx + j] = v;
    Xb[(size_t)t*ldxb + j] = (__bf16)v;
  }
}

// ---------------- z0 = gelu(ZP + prev*wlast) -> Z fp32 + Zb bf16 ----------------
__global__ void k_z0(const float* __restrict__ ZP, const float* __restrict__ wlast,
                     const float* __restrict__ prevg,
                     float* __restrict__ Z, __bf16* __restrict__ Zb){
  int t = blockIdx.y; int j = blockIdx.x*256 + threadIdx.x;
  float v = gelu_f(ZP[(size_t)t*MDIM + j] + prevg[t]*wlast[j]);
  Z[(size_t)t*MDIM + j] = v;
  Zb[(size_t)t*MDIM + j] = (__bf16)v;
}

// ---------------- batched mu/phi from Z fp32 ----------------
__global__ __launch_bounds__(256) void k_muphi(const float* __restrict__ Z,
    const float* __restrict__ muw, const float* __restrict__ mub,
    const float* __restrict__ phiw, const float* __restrict__ phib,
    float* __restrict__ muA, float* __restrict__ phiA){
  int t = blockIdx.x;
  __shared__ float red[16];
  float sm=0.f, sp=0.f;
  #pragma unroll
  for (int q=0;q<4;q++){
    int j = threadIdx.x + 256*q;
    float z = Z[(size_t)t*MDIM + j];
    sm = fmaf(z, muw[j], sm);
    sp = fmaf(z, phiw[j], sp);
  }
  for (int o=32;o>0;o>>=1){ sm+=__shfl_down(sm,o); sp+=__shfl_down(sp,o); }
  int wid = threadIdx.x>>6, lane = threadIdx.x&63;
  if (lane==0){ red[wid]=sm; red[wid+8]=sp; }
  __syncthreads();
  if (threadIdx.x==0){
    float a=0.f,c=0.f;
    for (int w=0;w<4;w++){ a+=red[w]; c+=red[w+8]; }
    muA[t]  = sigmoid_f(a + mub[0]);
    phiA[t] = softplus_f(c + phib[0]) + 2.0f;
  }
}

// ---------------- per-row full beta-head (dirty rows only, fp32) ----------------
__global__ __launch_bounds__(1024) void k_head_row(
    const float* __restrict__ ZP, const float* __restrict__ wlast,
    const float* __restrict__ fc1w, const float* __restrict__ fc1b,
    const float* __restrict__ fc2w, const float* __restrict__ fc2b,
    const float* __restrict__ lng,  const float* __restrict__ lnb,
    const float* __restrict__ muw,  const float* __restrict__ mub,
    const float* __restrict__ phiw, const float* __restrict__ phib,
    const float* __restrict__ prevg,
    const int* __restrict__ dlist, const int* __restrict__ dcnt,
    float* __restrict__ muA, float* __restrict__ phiA)
{
  if ((int)blockIdx.x >= *dcnt) return;
  int t = dlist[blockIdx.x];
  __shared__ float zs[MDIM];
  __shared__ float hs[MDIM];
  __shared__ float red[32];
  int j = threadIdx.x;
  int wid = j>>6, lane = j&63;
  float prev = prevg[t];
  zs[j] = gelu_f(ZP[(size_t)t*MDIM + j] + prev*wlast[j]);
  __syncthreads();
  for (int blk=0; blk<NBLK; blk++){
    const float* W1 = fc1w + (size_t)blk*MDIM*MDIM;
    const float* W2 = fc2w + (size_t)blk*MDIM*MDIM;
    float acc = fc1b[blk*MDIM + j];
    for (int k=0;k<MDIM;k++) acc = fmaf(zs[k], W1[(size_t)k*MDIM + j], acc);
    hs[j] = gelu_f(acc);
    __syncthreads();
    float y = fc2b[blk*MDIM + j];
    for (int k=0;k<MDIM;k++) y = fmaf(hs[k], W2[(size_t)k*MDIM + j], y);
    y += zs[j];
    float s = y, s2 = y*y;
    for (int o=32;o>0;o>>=1){ s+=__shfl_down(s,o); s2+=__shfl_down(s2,o); }
    if (lane==0){ red[wid]=s; red[wid+16]=s2; }
    __syncthreads();
    if (wid==0){
      float a = (lane<16)? red[lane] : 0.f;
      float c = (lane<16)? red[lane+16] : 0.f;
      for (int o=8;o>0;o>>=1){ a+=__shfl_down(a,o); c+=__shfl_down(c,o); }
      if (lane==0){ red[0]=a; red[16]=c; }
    }
    __syncthreads();
    float mean = red[0]*(1.0f/MDIM);
    float var  = red[16]*(1.0f/MDIM) - mean*mean;
    float rs = rsqrtf(var + 1e-5f);
    float zn = lng[blk*MDIM+j]*(y-mean)*rs + lnb[blk*MDIM+j];
    __syncthreads();
    zs[j] = zn;
    __syncthreads();
  }
  float sm = zs[j]*muw[j];
  float sp = zs[j]*phiw[j];
  for (int o=32;o>0;o>>=1){ sm+=__shfl_down(sm,o); sp+=__shfl_down(sp,o); }
  if (lane==0){ red[wid]=sm; red[wid+16]=sp; }
  __syncthreads();
  if (wid==0){
    float a = (lane<16)? red[lane] : 0.f;
    float c = (lane<16)? red[lane+16] : 0.f;
    for (int o=8;o>0;o>>=1){ a+=__shfl_down(a,o); c+=__shfl_down(c,o); }
    if (lane==0){
      muA[t]  = sigmoid_f(a + mub[0]);
      phiA[t] = softplus_f(c + phib[0]) + 2.0f;
    }
  }
}

// ---------------- segmented prefix-product scan + dirty detection + output ----------------
__global__ __launch_bounds__(1024) void k_scan(
    const float* __restrict__ muA, const float* __restrict__ phiA,
    const unsigned char* __restrict__ bmask,
    float* __restrict__ prevg, int* __restrict__ dlist, int* __restrict__ dcnt,
    float* __restrict__ out)
{
  __shared__ float v[2][TSEQ];
  __shared__ unsigned char f[2][TSEQ];
  __shared__ int cnt;
  int tid = threadIdx.x;
  if (tid==0) cnt = 0;
  for (int i=tid;i<TSEQ;i+=1024){
    v[0][i] = 1.0f - muA[i];
    f[0][i] = (i==0) || (bmask[i] != 0);
  }
  __syncthreads();
  int src=0;
  for (int off=1; off<TSEQ; off<<=1){
    int dst = src^1;
    for (int i=tid;i<TSEQ;i+=1024){
      float vv = v[src][i]; unsigned char ff = f[src][i];
      if (i>=off && !ff){ vv *= v[src][i-off]; ff = f[src][i-off]; }
      v[dst][i]=vv; f[dst][i]=ff;
    }
    __syncthreads();
    src = dst;
  }
  for (int i=tid;i<TSEQ;i+=1024){
    float rf = 1.0f - v[src][i];
    float prev = (i==0) ? -1.0f : (1.0f - v[src][i-1]);
    out[i]        = rf;
    out[TSEQ+i]   = muA[i];
    out[2*TSEQ+i] = phiA[i];
    float old = prevg[i];
    prevg[i] = prev;
    if (fabsf(prev - old) > 1e-6f){
      int pos = atomicAdd(&cnt, 1);
      dlist[pos] = i;
    }
  }
  __syncthreads();
  if (tid==0) *dcnt = cnt;
}

extern "C" void kernel_launch(void* const* d_in, const int* in_sizes, int n_in,
                              void* d_out, int out_size, void* d_ws, size_t ws_size,
                              hipStream_t stream) {
  const float* mol       = (const float*)d_in[0];
  const float* ratios    = (const float*)d_in[1];
  const float* desc      = (const float*)d_in[2];
  const float* svvec     = (const float*)d_in[3];
  const unsigned char* bmask = (const unsigned char*)d_in[4];
  const float* sp_proj_w = (const float*)d_in[5];
  const float* sp_proj_b = (const float*)d_in[6];
  const float* sp_fc1_w  = (const float*)d_in[7];
  const float* sp_fc1_b  = (const float*)d_in[8];
  const float* sp_fc2_w  = (const float*)d_in[9];
  const float* sp_fc2_b  = (const float*)d_in[10];
  const float* sp_ln_g   = (const float*)d_in[11];
  const float* sp_ln_b   = (const float*)d_in[12];
  const float* desc_w    = (const float*)d_in[13];
  const float* desc_b    = (const float*)d_in[14];
  const float* bh_proj_w = (const float*)d_in[15];
  const float* bh_proj_b = (const float*)d_in[16];
  const float* bh_fc1_w  = (const float*)d_in[17];
  const float* bh_fc1_b  = (const float*)d_in[18];
  const float* bh_fc2_w  = (const float*)d_in[19];
  const float* bh_fc2_b  = (const float*)d_in[20];
  const float* bh_ln_g   = (const float*)d_in[21];
  const float* bh_ln_b   = (const float*)d_in[22];
  const float* mu_w      = (const float*)d_in[23];
  const float* mu_b      = (const float*)d_in[24];
  const float* phi_w     = (const float*)d_in[25];
  const float* phi_b     = (const float*)d_in[26];
  float* out = (float*)d_out;

  char* p = (char*)d_ws;
  auto alloc = [&](size_t bytes)->char*{ char* r = p; p += (bytes + 255) & ~(size_t)255; return r; };
  const size_t MM = (size_t)MDIM*MDIM;
  float*  X    = (float*)alloc((size_t)TSEQ*MDIM*4);     // fp32 activations (sp x, later head z)
  __bf16* Xb   = (__bf16*)alloc((size_t)TSEQ*XLDB*2);    // bf16 [sp|demb]; later reused as Zb
  float*  Y    = (float*)alloc((size_t)TSEQ*MDIM*4);     // fp32 pre-LN
  float*  ZP   = (float*)alloc((size_t)TSEQ*MDIM*4);     // persistent head pre-activation
  __bf16* Hb16 = (__bf16*)alloc((size_t)TSEQ*MDIM*2);
  __bf16* W1T  = (__bf16*)alloc(NBLK*MM*2);
  __bf16* W2T  = (__bf16*)alloc(NBLK*MM*2);
  __bf16* U1T  = (__bf16*)alloc(NBLK*MM*2);
  __bf16* U2T  = (__bf16*)alloc(NBLK*MM*2);
  __bf16* WpT  = (__bf16*)alloc((size_t)MDIM*XLDB*2);    // [1024][1088]
  float*  P    = (float*)alloc((size_t)NSOL*MDIM*4);
  float*  mp   = (float*)alloc(MDIM*4);
  float*  prevg= (float*)alloc(TSEQ*4);
  float*  muA  = (float*)alloc(TSEQ*4);
  float*  phiA = (float*)alloc(TSEQ*4);
  int*    dlist= (int*)alloc(TSEQ*4);
  int*    dcnt = (int*)alloc(256);
  float*  Z    = X;      // alias: X fp32 dead after sp chain
  __bf16* Zb   = Xb;     // alias: Xb dead after zpre GEMM

  k_init<<<dim3((TSEQ+255)/256),256,0,stream>>>(prevg, dlist, dcnt);
  // weight convert+transpose (once per launch)
  k_cvtT<<<dim3(32,32,NBLK),256,0,stream>>>(sp_fc1_w, W1T, MDIM, MDIM);
  k_cvtT<<<dim3(32,32,NBLK),256,0,stream>>>(sp_fc2_w, W2T, MDIM, MDIM);
  k_cvtT<<<dim3(32,32,NBLK),256,0,stream>>>(bh_fc1_w, U1T, MDIM, MDIM);
  k_cvtT<<<dim3(32,32,NBLK),256,0,stream>>>(bh_fc2_w, U2T, MDIM, MDIM);
  k_cvtT<<<dim3(32,34,1),256,0,stream>>>(bh_proj_w + MM, WpT, XLDB, MDIM);

  k_solvP<<<dim3(4,NSOL),256,0,stream>>>(svvec, sp_proj_w, P);
  k_sp0<<<dim3(4,TSEQ),256,0,stream>>>(ratios, P, sp_proj_b, X, Xb);
  k_demb<<<dim3(TSEQ),64,0,stream>>>(desc, desc_w, desc_b, Xb);
  k_molpart<<<dim3(4),256,0,stream>>>(mol, bh_proj_w, bh_proj_b, mp);

  // sp residual chain (bf16 MFMA GEMMs)
  for (int i=0;i<NBLK;i++){
    k_mfma_gemm<true,false,false,true><<<dim3(16,16),256,0,stream>>>(
        Xb, XLDB, MDIM, W1T + i*MM, sp_fc1_b + i*MDIM, nullptr, 0,
        nullptr, 0, Hb16, MDIM);
    k_mfma_gemm<false,true,true,false><<<dim3(16,16),256,0,stream>>>(
        Hb16, MDIM, MDIM, W2T + i*MM, sp_fc2_b + i*MDIM, X, MDIM,
        Y, MDIM, nullptr, 0);
    k_ln<<<dim3(TSEQ),256,0,stream>>>(Y, MDIM, X, MDIM, Xb, XLDB,
        sp_ln_g + i*MDIM, sp_ln_b + i*MDIM);
  }
  // z_pre = [sp|demb] @ bh_proj_w[1024:2112] + (mol part incl. bias)
  k_mfma_gemm<false,false,true,false><<<dim3(16,16),256,0,stream>>>(
      Xb, XLDB, XLDB, WpT, mp, nullptr, 0, ZP, MDIM, nullptr, 0);

  const float* wlast = bh_proj_w + (size_t)2112*MDIM;
  // ---- iteration 1: batched head with speculative prev ----
  k_z0<<<dim3(4,TSEQ),256,0,stream>>>(ZP, wlast, prevg, Z, Zb);
  for (int i=0;i<NBLK;i++){
    k_mfma_gemm<true,false,false,true><<<dim3(16,16),256,0,stream>>>(
        Zb, MDIM, MDIM, U1T + i*MM, bh_fc1_b + i*MDIM, nullptr, 0,
        nullptr, 0, Hb16, MDIM);
    k_mfma_gemm<false,true,true,false><<<dim3(16,16),256,0,stream>>>(
        Hb16, MDIM, MDIM, U2T + i*MM, bh_fc2_b + i*MDIM, Z, MDIM,
        Y, MDIM, nullptr, 0);
    k_ln<<<dim3(TSEQ),256,0,stream>>>(Y, MDIM, Z, MDIM, Zb, MDIM,
        bh_ln_g + i*MDIM, bh_ln_b + i*MDIM);
  }
  k_muphi<<<dim3(TSEQ),256,0,stream>>>(Z, mu_w, mu_b, phi_w, phi_b, muA, phiA);
  k_scan<<<dim3(1),1024,0,stream>>>(muA, phiA, bmask, prevg, dlist, dcnt, out);

  // ---- refinement iterations: per-row fp32 head on dirty rows only ----
  for (int it=1; it<KITER; it++){
    k_head_row<<<dim3(TSEQ),1024,0,stream>>>(ZP, wlast, bh_fc1_w, bh_fc1_b, bh_fc2_w, bh_fc2_b,
        bh_ln_g, bh_ln_b, mu_w, mu_b, phi_w, phi_b, prevg, dlist, dcnt, muA, phiA);
    k_scan<<<dim3(1),1024,0,stream>>>(muA, phiA, bmask, prevg, dlist, dcnt, out);
  }
  (void)in_sizes; (void)n_in; (void)out_size; (void)ws_size;
}

// Round 3
// 745.642 us; speedup vs baseline: 4.3308x; 1.2892x over previous
//
#include <hip/hip_runtime.h>
#include <math.h>

#define MDIM 1024
#define TSEQ 2048
#define NSOL 5
#define DED  64
#define NBLK 3
#define KITER 6
#define XLDB 1088   // bf16 X leading dim: 1024 sp cols + 64 demb cols
#define LDP  72     // padded LDS stride (bf16 elems): 144B rows -> 2-way (free) b128 reads
#define RST  64     // dirty-stage grid row stride

typedef __bf16 bf16x8 __attribute__((ext_vector_type(8)));
typedef float  f32x4  __attribute__((ext_vector_type(4)));

__device__ __forceinline__ float gelu_f(float x){
  return 0.5f * x * (1.0f + erff(x * 0.70710678118654752440f));
}
__device__ __forceinline__ float sigmoid_f(float x){ return 1.0f/(1.0f+expf(-x)); }
__device__ __forceinline__ float softplus_f(float x){ return fmaxf(x,0.0f) + log1pf(expf(-fabsf(x))); }

// ---------------- init speculative state ----------------
__global__ void k_init(float* prevg, int* dlist, int* dcnt){
  int i = blockIdx.x*blockDim.x + threadIdx.x;
  if (i < TSEQ){ prevg[i] = (i==0)? -1.0f : 1.0f; dlist[i] = i; }
  if (i == 0) *dcnt = TSEQ;
}

// ---------------- convert fp32 [K][N] -> bf16 transposed [N][K], z-stacked ----------------
__global__ __launch_bounds__(256) void k_cvtT(const float* __restrict__ src,
                                              __bf16* __restrict__ dst, int K, int N){
  __shared__ float t[32][33];
  int z = blockIdx.z;
  const float* s = src + (size_t)z*K*N;
  __bf16* d = dst + (size_t)z*N*K;
  int k0 = blockIdx.y*32, n0 = blockIdx.x*32;
  int tx = threadIdx.x & 31, ty = threadIdx.x >> 5; // ty 0..7
  #pragma unroll
  for (int r=0;r<32;r+=8) t[ty+r][tx] = s[(size_t)(k0+ty+r)*N + n0+tx];
  __syncthreads();
  #pragma unroll
  for (int r=0;r<32;r+=8) d[(size_t)(n0+ty+r)*K + k0+tx] = (__bf16)t[tx][ty+r];
}

// ---------------- P[s][j] = solvent_vecs[s] @ sp_proj_w block s ----------------
__global__ void k_solvP(const float* __restrict__ sv, const float* __restrict__ W,
                        float* __restrict__ P){
  int s = blockIdx.y;
  int j = blockIdx.x*256 + threadIdx.x;
  const float* w = W + (size_t)s*MDIM*MDIM + j;
  const float* v = sv + s*MDIM;
  float acc = 0.f;
  for (int k=0;k<MDIM;k++) acc = fmaf(v[k], w[(size_t)k*MDIM], acc);
  P[s*MDIM + j] = acc;
}

// ---------------- sp0[t][j] = gelu(sum_s ratios[t][s]*P[s][j] + b[j]) -> X fp32 + Xb bf16 ----------------
__global__ void k_sp0(const float* __restrict__ ratios, const float* __restrict__ P,
                      const float* __restrict__ bias, float* __restrict__ X,
                      __bf16* __restrict__ Xb){
  int t = blockIdx.y;
  int j = blockIdx.x*256 + threadIdx.x;
  const float* r = ratios + t*NSOL;
  float acc = bias[j];
  #pragma unroll
  for (int s=0;s<NSOL;s++) acc = fmaf(r[s], P[s*MDIM+j], acc);
  float v = gelu_f(acc);
  X[(size_t)t*MDIM + j] = v;
  Xb[(size_t)t*XLDB + j] = (__bf16)v;
}

// ---------------- demb[t][e] = gelu(desc[t] @ desc_w + desc_b) -> Xb cols 1024.. ----------------
__global__ void k_demb(const float* __restrict__ desc, const float* __restrict__ dw,
                       const float* __restrict__ db, __bf16* __restrict__ Xb){
  int t = blockIdx.x; int e = threadIdx.x;
  const float* d = desc + t*6;
  float acc = db[e];
  #pragma unroll
  for (int c=0;c<6;c++) acc = fmaf(d[c], dw[c*DED+e], acc);
  Xb[(size_t)t*XLDB + MDIM + e] = (__bf16)gelu_f(acc);
}

// ---------------- molpart[j] = mol_vec @ bh_proj_w[0:1024] + bh_proj_b ----------------
__global__ void k_molpart(const float* __restrict__ mol, const float* __restrict__ bhw,
                          const float* __restrict__ bhb, float* __restrict__ mp){
  int j = blockIdx.x*256 + threadIdx.x;
  float acc = bhb[j];
  for (int k=0;k<MDIM;k++) acc = fmaf(mol[k], bhw[(size_t)k*MDIM + j], acc);
  mp[j] = acc;
}

// ---------------- bf16 MFMA GEMM: C[t][j] = epi(sum_k A[t][k]*Bt[j][k] + bias[j]) ----------------
template<bool GELU, bool RES, bool OUTF, bool OUTB>
__global__ __launch_bounds__(256) void k_mfma_gemm(
    const __bf16* __restrict__ A, int lda, int K,
    const __bf16* __restrict__ Bt,           // [N][K] bf16
    const float* __restrict__ bias,          // [N] fp32
    const float* __restrict__ R, int ldr,    // fp32 residual
    float* __restrict__ Cf, int ldcf,
    __bf16* __restrict__ Cb, int ldcb)
{
  __shared__ __attribute__((aligned(16))) __bf16 As[128*LDP];
  __shared__ __attribute__((aligned(16))) __bf16 Bs[64*LDP];
  int tid = threadIdx.x;
  int wave = tid>>6, lane = tid&63;
  int row0 = blockIdx.y*128, col0 = blockIdx.x*64;
  int wr = (wave>>1)*64, wc = (wave&1)*32;
  int lr = lane&15, lk = (lane>>4)*8;
  f32x4 acc[4][2] = {};
  for (int k0=0;k0<K;k0+=64){
    __syncthreads();
    #pragma unroll
    for (int p=0;p<4;p++){
      int c = p*256 + tid;
      int r = c>>3, kc = (c&7)*8;
      *(bf16x8*)&As[r*LDP + kc] = *(const bf16x8*)&A[(size_t)(row0+r)*lda + k0 + kc];
    }
    #pragma unroll
    for (int p=0;p<2;p++){
      int c = p*256 + tid;
      int r = c>>3, kc = (c&7)*8;
      *(bf16x8*)&Bs[r*LDP + kc] = *(const bf16x8*)&Bt[(size_t)(col0+r)*K + k0 + kc];
    }
    __syncthreads();
    #pragma unroll
    for (int ks=0;ks<2;ks++){
      int kk = ks*32 + lk;
      bf16x8 af[4], bg[2];
      #pragma unroll
      for (int m=0;m<4;m++) af[m] = *(const bf16x8*)&As[(wr + m*16 + lr)*LDP + kk];
      #pragma unroll
      for (int n=0;n<2;n++) bg[n] = *(const bf16x8*)&Bs[(wc + n*16 + lr)*LDP + kk];
      #pragma unroll
      for (int m=0;m<4;m++)
        #pragma unroll
        for (int n=0;n<2;n++)
          acc[m][n] = __builtin_amdgcn_mfma_f32_16x16x32_bf16(af[m], bg[n], acc[m][n], 0,0,0);
    }
  }
  int rq = (lane>>4)*4;  // verified C/D layout: col = lane&15, row = (lane>>4)*4 + q
  #pragma unroll
  for (int m=0;m<4;m++){
    #pragma unroll
    for (int n=0;n<2;n++){
      int c = col0 + wc + n*16 + lr;
      float bv = bias[c];
      #pragma unroll
      for (int q=0;q<4;q++){
        int r = row0 + wr + m*16 + rq + q;
        float v = acc[m][n][q] + bv;
        if (RES)  v += R[(size_t)r*ldr + c];
        if (GELU) v = gelu_f(v);
        if (OUTF) Cf[(size_t)r*ldcf + c] = v;
        if (OUTB) Cb[(size_t)r*ldcb + c] = (__bf16)v;
      }
    }
  }
}

// ---------------- batched LayerNorm -> fp32 + bf16, optional fused mu/phi ----------------
template<bool MUPHI>
__global__ __launch_bounds__(256) void k_ln(const float* __restrict__ Y, int ldy,
    float* __restrict__ Xo, int ldx, __bf16* __restrict__ Xb, int ldxb,
    const float* __restrict__ g, const float* __restrict__ b,
    const float* __restrict__ muw, const float* __restrict__ mub,
    const float* __restrict__ phiw, const float* __restrict__ phib,
    float* __restrict__ muA, float* __restrict__ phiA)
{
  int t = blockIdx.x;
  __shared__ float red[16];
  float y[4]; float s=0.f, s2=0.f;
  #pragma unroll
  for (int q=0;q<4;q++){
    y[q] = Y[(size_t)t*ldy + threadIdx.x + 256*q];
    s += y[q]; s2 += y[q]*y[q];
  }
  for (int o=32;o>0;o>>=1){ s += __shfl_down(s,o); s2 += __shfl_down(s2,o); }
  int wid = threadIdx.x>>6, lane = threadIdx.x&63;
  if (lane==0){ red[wid]=s; red[wid+8]=s2; }
  __syncthreads();
  if (threadIdx.x==0){
    float a=0.f,c=0.f;
    for (int w=0;w<4;w++){ a+=red[w]; c+=red[w+8]; }
    red[0]=a; red[8]=c;
  }
  __syncthreads();
  float mean = red[0]*(1.0f/MDIM);
  float var  = red[8]*(1.0f/MDIM) - mean*mean;
  float rs = rsqrtf(var + 1e-5f);
  float sm = 0.f, sp = 0.f;
  #pragma unroll
  for (int q=0;q<4;q++){
    int j = threadIdx.x + 256*q;
    float v = g[j]*(y[q]-mean)*rs + b[j];
    Xo[(size_t)t*ldx + j] = v;
    Xb[(size_t)t*ldxb + j] = (__bf16)v;
    if (MUPHI){ sm = fmaf(v, muw[j], sm); sp = fmaf(v, phiw[j], sp); }
  }
  if (MUPHI){
    for (int o=32;o>0;o>>=1){ sm+=__shfl_down(sm,o); sp+=__shfl_down(sp,o); }
    __syncthreads();
    if (lane==0){ red[wid]=sm; red[wid+8]=sp; }
    __syncthreads();
    if (threadIdx.x==0){
      float a=0.f,c=0.f;
      for (int w=0;w<4;w++){ a+=red[w]; c+=red[w+8]; }
      muA[t]  = sigmoid_f(a + mub[0]);
      phiA[t] = softplus_f(c + phib[0]) + 2.0f;
    }
  }
}

// ---------------- z0 = gelu(ZP + prev*wlast) -> Z fp32 + Zb bf16 (all rows) ----------------
__global__ void k_z0(const float* __restrict__ ZP, const float* __restrict__ wlast,
                     const float* __restrict__ prevg,
                     float* __restrict__ Z, __bf16* __restrict__ Zb){
  int t = blockIdx.y; int j = blockIdx.x*256 + threadIdx.x;
  float v = gelu_f(ZP[(size_t)t*MDIM + j] + prevg[t]*wlast[j]);
  Z[(size_t)t*MDIM + j] = v;
  Zb[(size_t)t*MDIM + j] = (__bf16)v;
}

// ================= dirty-row refinement stages =================

// z0 for dirty rows only
__global__ __launch_bounds__(256) void k_z0_dirty(
    const float* __restrict__ ZP, const float* __restrict__ wlast,
    const float* __restrict__ prevg,
    const int* __restrict__ dlist, const int* __restrict__ dcnt,
    float* __restrict__ Z, __bf16* __restrict__ Zb)
{
  int nd = *dcnt;
  for (int rs = blockIdx.x; rs < nd; rs += RST){
    int t = dlist[rs];
    float prev = prevg[t];
    #pragma unroll
    for (int q=0;q<4;q++){
      int j = threadIdx.x + 256*q;
      float v = gelu_f(ZP[(size_t)t*MDIM + j] + prev*wlast[j]);
      Z[(size_t)t*MDIM + j] = v;
      Zb[(size_t)t*MDIM + j] = (__bf16)v;
    }
  }
}

// fc matvec for dirty rows: out[j] = epi(bias[j] + sum_k In[t][k]*Wt[j][k] (+ Rz))
// grid (4, RST): 256 outputs per block, 1 thread per output, full K per thread.
template<bool GELU, bool RES, bool OUTB>
__global__ __launch_bounds__(256) void k_fc_dirty(
    const __bf16* __restrict__ In, const __bf16* __restrict__ Wt,
    const float* __restrict__ bias, const float* __restrict__ Rz,
    const int* __restrict__ dlist, const int* __restrict__ dcnt,
    __bf16* __restrict__ Ob, float* __restrict__ Of)
{
  int nd = *dcnt;
  int j = blockIdx.x*256 + threadIdx.x;
  for (int rs = blockIdx.y; rs < nd; rs += RST){
    int t = dlist[rs];
    const __bf16* in = In + (size_t)t*MDIM;
    const __bf16* w  = Wt + (size_t)j*MDIM;
    float acc = 0.f;
    for (int k=0;k<MDIM;k+=8){
      bf16x8 wv = *(const bf16x8*)&w[k];
      bf16x8 iv = *(const bf16x8*)&in[k];
      #pragma unroll
      for (int u=0;u<8;u++) acc = fmaf((float)wv[u], (float)iv[u], acc);
    }
    acc += bias[j];
    if (RES)  acc += Rz[(size_t)t*MDIM + j];
    if (GELU) acc = gelu_f(acc);
    if (OUTB) Ob[(size_t)t*MDIM + j] = (__bf16)acc;
    else      Of[(size_t)t*MDIM + j] = acc;
  }
}

// LayerNorm for dirty rows; optional fused mu/phi on final block
template<bool MUPHI>
__global__ __launch_bounds__(256) void k_ln_dirty(
    const float* __restrict__ Y,
    const float* __restrict__ g, const float* __restrict__ b,
    const int* __restrict__ dlist, const int* __restrict__ dcnt,
    float* __restrict__ Z, __bf16* __restrict__ Zb,
    const float* __restrict__ muw, const float* __restrict__ mub,
    const float* __restrict__ phiw, const float* __restrict__ phib,
    float* __restrict__ muA, float* __restrict__ phiA)
{
  int nd = *dcnt;
  __shared__ float red[16];
  int wid = threadIdx.x>>6, lane = threadIdx.x&63;
  for (int rs = blockIdx.x; rs < nd; rs += RST){
    int t = dlist[rs];
    float y[4]; float s=0.f, s2=0.f;
    #pragma unroll
    for (int q=0;q<4;q++){
      y[q] = Y[(size_t)t*MDIM + threadIdx.x + 256*q];
      s += y[q]; s2 += y[q]*y[q];
    }
    for (int o=32;o>0;o>>=1){ s += __shfl_down(s,o); s2 += __shfl_down(s2,o); }
    if (lane==0){ red[wid]=s; red[wid+8]=s2; }
    __syncthreads();
    if (threadIdx.x==0){
      float a=0.f,c=0.f;
      for (int w=0;w<4;w++){ a+=red[w]; c+=red[w+8]; }
      red[0]=a; red[8]=c;
    }
    __syncthreads();
    float mean = red[0]*(1.0f/MDIM);
    float var  = red[8]*(1.0f/MDIM) - mean*mean;
    float rs2 = rsqrtf(var + 1e-5f);
    float sm=0.f, sp=0.f;
    #pragma unroll
    for (int q=0;q<4;q++){
      int j = threadIdx.x + 256*q;
      float v = g[j]*(y[q]-mean)*rs2 + b[j];
      Z[(size_t)t*MDIM + j] = v;
      Zb[(size_t)t*MDIM + j] = (__bf16)v;
      if (MUPHI){ sm = fmaf(v, muw[j], sm); sp = fmaf(v, phiw[j], sp); }
    }
    __syncthreads();
    if (MUPHI){
      for (int o=32;o>0;o>>=1){ sm+=__shfl_down(sm,o); sp+=__shfl_down(sp,o); }
      if (lane==0){ red[wid]=sm; red[wid+8]=sp; }
      __syncthreads();
      if (threadIdx.x==0){
        float a=0.f,c=0.f;
        for (int w=0;w<4;w++){ a+=red[w]; c+=red[w+8]; }
        muA[t]  = sigmoid_f(a + mub[0]);
        phiA[t] = softplus_f(c + phib[0]) + 2.0f;
      }
      __syncthreads();
    }
  }
}

// ---------------- segmented prefix-product scan + dirty detection + output ----------------
__global__ __launch_bounds__(1024) void k_scan(
    const float* __restrict__ muA, const float* __restrict__ phiA,
    const unsigned char* __restrict__ bmask,
    float* __restrict__ prevg, int* __restrict__ dlist, int* __restrict__ dcnt,
    float* __restrict__ out)
{
  __shared__ float v[2][TSEQ];
  __shared__ unsigned char f[2][TSEQ];
  __shared__ int cnt;
  int tid = threadIdx.x;
  if (tid==0) cnt = 0;
  for (int i=tid;i<TSEQ;i+=1024){
    v[0][i] = 1.0f - muA[i];
    f[0][i] = (i==0) || (bmask[i] != 0);
  }
  __syncthreads();
  int src=0;
  for (int off=1; off<TSEQ; off<<=1){
    int dst = src^1;
    for (int i=tid;i<TSEQ;i+=1024){
      float vv = v[src][i]; unsigned char ff = f[src][i];
      if (i>=off && !ff){ vv *= v[src][i-off]; ff = f[src][i-off]; }
      v[dst][i]=vv; f[dst][i]=ff;
    }
    __syncthreads();
    src = dst;
  }
  for (int i=tid;i<TSEQ;i+=1024){
    float rf = 1.0f - v[src][i];
    float prev = (i==0) ? -1.0f : (1.0f - v[src][i-1]);
    out[i]        = rf;
    out[TSEQ+i]   = muA[i];
    out[2*TSEQ+i] = phiA[i];
    float old = prevg[i];
    prevg[i] = prev;
    if (fabsf(prev - old) > 1e-4f){
      int pos = atomicAdd(&cnt, 1);
      dlist[pos] = i;
    }
  }
  __syncthreads();
  if (tid==0) *dcnt = cnt;
}

extern "C" void kernel_launch(void* const* d_in, const int* in_sizes, int n_in,
                              void* d_out, int out_size, void* d_ws, size_t ws_size,
                              hipStream_t stream) {
  const float* mol       = (const float*)d_in[0];
  const float* ratios    = (const float*)d_in[1];
  const float* desc      = (const float*)d_in[2];
  const float* svvec     = (const float*)d_in[3];
  const unsigned char* bmask = (const unsigned char*)d_in[4];
  const float* sp_proj_w = (const float*)d_in[5];
  const float* sp_proj_b = (const float*)d_in[6];
  const float* sp_fc1_w  = (const float*)d_in[7];
  const float* sp_fc1_b  = (const float*)d_in[8];
  const float* sp_fc2_w  = (const float*)d_in[9];
  const float* sp_fc2_b  = (const float*)d_in[10];
  const float* sp_ln_g   = (const float*)d_in[11];
  const float* sp_ln_b   = (const float*)d_in[12];
  const float* desc_w    = (const float*)d_in[13];
  const float* desc_b    = (const float*)d_in[14];
  const float* bh_proj_w = (const float*)d_in[15];
  const float* bh_proj_b = (const float*)d_in[16];
  const float* bh_fc1_w  = (const float*)d_in[17];
  const float* bh_fc1_b  = (const float*)d_in[18];
  const float* bh_fc2_w  = (const float*)d_in[19];
  const float* bh_fc2_b  = (const float*)d_in[20];
  const float* bh_ln_g   = (const float*)d_in[21];
  const float* bh_ln_b   = (const float*)d_in[22];
  const float* mu_w      = (const float*)d_in[23];
  const float* mu_b      = (const float*)d_in[24];
  const float* phi_w     = (const float*)d_in[25];
  const float* phi_b     = (const float*)d_in[26];
  float* out = (float*)d_out;

  char* p = (char*)d_ws;
  auto alloc = [&](size_t bytes)->char*{ char* r = p; p += (bytes + 255) & ~(size_t)255; return r; };
  const size_t MM = (size_t)MDIM*MDIM;
  float*  X    = (float*)alloc((size_t)TSEQ*MDIM*4);     // fp32 activations (sp x, later head z)
  __bf16* Xb   = (__bf16*)alloc((size_t)TSEQ*XLDB*2);    // bf16 [sp|demb]; later reused as Zb
  float*  Y    = (float*)alloc((size_t)TSEQ*MDIM*4);     // fp32 pre-LN
  float*  ZP   = (float*)alloc((size_t)TSEQ*MDIM*4);     // persistent head pre-activation
  __bf16* Hb16 = (__bf16*)alloc((size_t)TSEQ*MDIM*2);
  __bf16* W1T  = (__bf16*)alloc(NBLK*MM*2);
  __bf16* W2T  = (__bf16*)alloc(NBLK*MM*2);
  __bf16* U1T  = (__bf16*)alloc(NBLK*MM*2);
  __bf16* U2T  = (__bf16*)alloc(NBLK*MM*2);
  __bf16* WpT  = (__bf16*)alloc((size_t)MDIM*XLDB*2);    // [1024][1088]
  float*  P    = (float*)alloc((size_t)NSOL*MDIM*4);
  float*  mp   = (float*)alloc(MDIM*4);
  float*  prevg= (float*)alloc(TSEQ*4);
  float*  muA  = (float*)alloc(TSEQ*4);
  float*  phiA = (float*)alloc(TSEQ*4);
  int*    dlist= (int*)alloc(TSEQ*4);
  int*    dcnt = (int*)alloc(256);
  float*  Z    = X;      // alias: X fp32 dead after sp chain
  __bf16* Zb   = Xb;     // alias: Xb dead after zpre GEMM

  k_init<<<dim3((TSEQ+255)/256),256,0,stream>>>(prevg, dlist, dcnt);
  // weight convert+transpose (once per launch)
  k_cvtT<<<dim3(32,32,NBLK),256,0,stream>>>(sp_fc1_w, W1T, MDIM, MDIM);
  k_cvtT<<<dim3(32,32,NBLK),256,0,stream>>>(sp_fc2_w, W2T, MDIM, MDIM);
  k_cvtT<<<dim3(32,32,NBLK),256,0,stream>>>(bh_fc1_w, U1T, MDIM, MDIM);
  k_cvtT<<<dim3(32,32,NBLK),256,0,stream>>>(bh_fc2_w, U2T, MDIM, MDIM);
  k_cvtT<<<dim3(32,34,1),256,0,stream>>>(bh_proj_w + MM, WpT, XLDB, MDIM);

  k_solvP<<<dim3(4,NSOL),256,0,stream>>>(svvec, sp_proj_w, P);
  k_sp0<<<dim3(4,TSEQ),256,0,stream>>>(ratios, P, sp_proj_b, X, Xb);
  k_demb<<<dim3(TSEQ),64,0,stream>>>(desc, desc_w, desc_b, Xb);
  k_molpart<<<dim3(4),256,0,stream>>>(mol, bh_proj_w, bh_proj_b, mp);

  // sp residual chain (bf16 MFMA GEMMs)
  for (int i=0;i<NBLK;i++){
    k_mfma_gemm<true,false,false,true><<<dim3(16,16),256,0,stream>>>(
        Xb, XLDB, MDIM, W1T + i*MM, sp_fc1_b + i*MDIM, nullptr, 0,
        nullptr, 0, Hb16, MDIM);
    k_mfma_gemm<false,true,true,false><<<dim3(16,16),256,0,stream>>>(
        Hb16, MDIM, MDIM, W2T + i*MM, sp_fc2_b + i*MDIM, X, MDIM,
        Y, MDIM, nullptr, 0);
    k_ln<false><<<dim3(TSEQ),256,0,stream>>>(Y, MDIM, X, MDIM, Xb, XLDB,
        sp_ln_g + i*MDIM, sp_ln_b + i*MDIM,
        nullptr, nullptr, nullptr, nullptr, nullptr, nullptr);
  }
  // z_pre = [sp|demb] @ bh_proj_w[1024:2112] + (mol part incl. bias)
  k_mfma_gemm<false,false,true,false><<<dim3(16,16),256,0,stream>>>(
      Xb, XLDB, XLDB, WpT, mp, nullptr, 0, ZP, MDIM, nullptr, 0);

  const float* wlast = bh_proj_w + (size_t)2112*MDIM;
  // ---- iteration 1: batched head with speculative prev ----
  k_z0<<<dim3(4,TSEQ),256,0,stream>>>(ZP, wlast, prevg, Z, Zb);
  for (int i=0;i<NBLK;i++){
    k_mfma_gemm<true,false,false,true><<<dim3(16,16),256,0,stream>>>(
        Zb, MDIM, MDIM, U1T + i*MM, bh_fc1_b + i*MDIM, nullptr, 0,
        nullptr, 0, Hb16, MDIM);
    k_mfma_gemm<false,true,true,false><<<dim3(16,16),256,0,stream>>>(
        Hb16, MDIM, MDIM, U2T + i*MM, bh_fc2_b + i*MDIM, Z, MDIM,
        Y, MDIM, nullptr, 0);
    if (i < NBLK-1)
      k_ln<false><<<dim3(TSEQ),256,0,stream>>>(Y, MDIM, Z, MDIM, Zb, MDIM,
          bh_ln_g + i*MDIM, bh_ln_b + i*MDIM,
          nullptr, nullptr, nullptr, nullptr, nullptr, nullptr);
    else
      k_ln<true><<<dim3(TSEQ),256,0,stream>>>(Y, MDIM, Z, MDIM, Zb, MDIM,
          bh_ln_g + i*MDIM, bh_ln_b + i*MDIM,
          mu_w, mu_b, phi_w, phi_b, muA, phiA);
  }
  k_scan<<<dim3(1),1024,0,stream>>>(muA, phiA, bmask, prevg, dlist, dcnt, out);

  // ---- refinement iterations: staged dirty-row head ----
  for (int it=1; it<KITER; it++){
    k_z0_dirty<<<dim3(RST),256,0,stream>>>(ZP, wlast, prevg, dlist, dcnt, Z, Zb);
    for (int i=0;i<NBLK;i++){
      k_fc_dirty<true,false,true><<<dim3(4,RST),256,0,stream>>>(
          Zb, U1T + i*MM, bh_fc1_b + i*MDIM, nullptr, dlist, dcnt, Hb16, nullptr);
      k_fc_dirty<false,true,false><<<dim3(4,RST),256,0,stream>>>(
          Hb16, U2T + i*MM, bh_fc2_b + i*MDIM, Z, dlist, dcnt, nullptr, Y);
      if (i < NBLK-1)
        k_ln_dirty<false><<<dim3(RST),256,0,stream>>>(Y, bh_ln_g + i*MDIM, bh_ln_b + i*MDIM,
            dlist, dcnt, Z, Zb, nullptr, nullptr, nullptr, nullptr, nullptr, nullptr);
      else
        k_ln_dirty<true><<<dim3(RST),256,0,stream>>>(Y, bh_ln_g + i*MDIM, bh_ln_b + i*MDIM,
            dlist, dcnt, Z, Zb, mu_w, mu_b, phi_w, phi_b, muA, phiA);
    }
    k_scan<<<dim3(1),1024,0,stream>>>(muA, phiA, bmask, prevg, dlist, dcnt, out);
  }
  (void)in_sizes; (void)n_in; (void)out_size; (void)ws_size;
}

// Round 4
// 615.335 us; speedup vs baseline: 5.2480x; 1.2118x over previous
//
#include <hip/hip_runtime.h>
#include <math.h>

#define MDIM 1024
#define TSEQ 2048
#define NSOL 5
#define DED  64
#define NBLK 3
#define KITER 5
#define XLDB 1088   // bf16 X leading dim: 1024 sp cols + 64 demb cols
#define RST  64     // dirty-stage grid row stride
#define NRED 6144   // 5120 P cols + 1024 mp cols

typedef __bf16 bf16x8 __attribute__((ext_vector_type(8)));
typedef float  f32x4  __attribute__((ext_vector_type(4)));

#define GLDS16(gptr, lptr) __builtin_amdgcn_global_load_lds( \
    (const __attribute__((address_space(1))) unsigned int*)(const void*)(gptr), \
    (__attribute__((address_space(3))) unsigned int*)(void*)(lptr), 16, 0, 0)

__device__ __forceinline__ float gelu_f(float x){
  return 0.5f * x * (1.0f + erff(x * 0.70710678118654752440f));
}
__device__ __forceinline__ float sigmoid_f(float x){ return 1.0f/(1.0f+expf(-x)); }
__device__ __forceinline__ float softplus_f(float x){ return fmaxf(x,0.0f) + log1pf(expf(-fabsf(x))); }

// ---------------- init speculative state ----------------
__global__ void k_init(float* prevg, int* dlist, int* dcnt){
  int i = blockIdx.x*blockDim.x + threadIdx.x;
  if (i < TSEQ){ prevg[i] = (i==0)? -1.0f : 1.0f; dlist[i] = i; }
  if (i == 0) *dcnt = TSEQ;
}

// ---------------- fused convert fp32 [K][N] -> bf16 transposed [N][K], 12 blocks of 4 srcs ----------------
__global__ __launch_bounds__(256) void k_cvtT12(const float* __restrict__ s0,
    const float* __restrict__ s1, const float* __restrict__ s2, const float* __restrict__ s3,
    __bf16* __restrict__ dst){
  __shared__ float t[32][33];
  const size_t MM = (size_t)MDIM*MDIM;
  int z = blockIdx.z;
  const float* s = (z<3)? s0 + (size_t)z*MM : (z<6)? s1 + (size_t)(z-3)*MM :
                   (z<9)? s2 + (size_t)(z-6)*MM : s3 + (size_t)(z-9)*MM;
  __bf16* d = dst + (size_t)z*MM;
  int k0 = blockIdx.y*32, n0 = blockIdx.x*32;
  int tx = threadIdx.x & 31, ty = threadIdx.x >> 5;
  #pragma unroll
  for (int r=0;r<32;r+=8) t[ty+r][tx] = s[(size_t)(k0+ty+r)*MDIM + n0+tx];
  __syncthreads();
  #pragma unroll
  for (int r=0;r<32;r+=8) d[(size_t)(n0+ty+r)*MDIM + k0+tx] = (__bf16)t[tx][ty+r];
}

// single-matrix version (for WpT, K=1088)
__global__ __launch_bounds__(256) void k_cvtT(const float* __restrict__ src,
                                              __bf16* __restrict__ dst, int K, int N){
  __shared__ float t[32][33];
  int k0 = blockIdx.y*32, n0 = blockIdx.x*32;
  int tx = threadIdx.x & 31, ty = threadIdx.x >> 5;
  #pragma unroll
  for (int r=0;r<32;r+=8) t[ty+r][tx] = src[(size_t)(k0+ty+r)*N + n0+tx];
  __syncthreads();
  #pragma unroll
  for (int r=0;r<32;r+=8) dst[(size_t)(n0+ty+r)*K + k0+tx] = (__bf16)t[tx][ty+r];
}

// ---------------- partial matvecs: P parts (solvent) ----------------
__global__ __launch_bounds__(256) void k_solvP(const float* __restrict__ sv,
    const float* __restrict__ W, float* __restrict__ PART){
  int s = blockIdx.y;
  int j = blockIdx.x*256 + threadIdx.x;
  int z = blockIdx.z, k0 = z*64;
  const float* w = W + (size_t)s*MDIM*MDIM + (size_t)k0*MDIM + j;
  const float* v = sv + s*MDIM + k0;
  float acc = 0.f;
  for (int k=0;k<64;k++) acc = fmaf(v[k], w[(size_t)k*MDIM], acc);
  PART[(size_t)z*NRED + s*MDIM + j] = acc;
}

// ---------------- partial matvec: mol part ----------------
__global__ __launch_bounds__(256) void k_molpart(const float* __restrict__ mol,
    const float* __restrict__ bhw, float* __restrict__ PART){
  int j = blockIdx.x*256 + threadIdx.x;
  int z = blockIdx.z, k0 = z*64;
  const float* w = bhw + (size_t)k0*MDIM + j;
  float acc = 0.f;
  for (int k=0;k<64;k++) acc = fmaf(mol[k0+k], w[(size_t)k*MDIM], acc);
  PART[(size_t)z*NRED + 5120 + j] = acc;
}

// ---------------- reduce partials -> P, mp(+bias) ----------------
__global__ __launch_bounds__(256) void k_red(const float* __restrict__ PART,
    const float* __restrict__ bhb, float* __restrict__ P, float* __restrict__ mp){
  int i = blockIdx.x*256 + threadIdx.x;
  float a = 0.f;
  #pragma unroll
  for (int z=0;z<16;z++) a += PART[(size_t)z*NRED + i];
  if (i < 5120) P[i] = a;
  else mp[i-5120] = a + bhb[i-5120];
}

// ---------------- sp0[t][j] = gelu(sum_s ratios[t][s]*P[s][j] + b[j]) -> X fp32 + Xb bf16 ----------------
__global__ void k_sp0(const float* __restrict__ ratios, const float* __restrict__ P,
                      const float* __restrict__ bias, float* __restrict__ X,
                      __bf16* __restrict__ Xb){
  int t = blockIdx.y;
  int j = blockIdx.x*256 + threadIdx.x;
  const float* r = ratios + t*NSOL;
  float acc = bias[j];
  #pragma unroll
  for (int s=0;s<NSOL;s++) acc = fmaf(r[s], P[s*MDIM+j], acc);
  float v = gelu_f(acc);
  X[(size_t)t*MDIM + j] = v;
  Xb[(size_t)t*XLDB + j] = (__bf16)v;
}

// ---------------- demb[t][e] = gelu(desc[t] @ desc_w + desc_b) -> Xb cols 1024.. ----------------
__global__ void k_demb(const float* __restrict__ desc, const float* __restrict__ dw,
                       const float* __restrict__ db, __bf16* __restrict__ Xb){
  int t = blockIdx.x; int e = threadIdx.x;
  const float* d = desc + t*6;
  float acc = db[e];
  #pragma unroll
  for (int c=0;c<6;c++) acc = fmaf(d[c], dw[c*DED+e], acc);
  Xb[(size_t)t*XLDB + MDIM + e] = (__bf16)gelu_f(acc);
}

// ---------------- bf16 MFMA GEMM, global_load_lds + chunk-swizzle + 2-phase dbuf ----------------
// BM=128, BN=64, BK=64, 256 threads (4 waves 2x2, each 64x32 = 4x2 16x16 frags).
template<bool GELU, bool RES, bool OUTF, bool OUTB>
__global__ __launch_bounds__(256) void k_mfma_gemm(
    const __bf16* __restrict__ A, int lda, int K,
    const __bf16* __restrict__ Bt,           // [N][K] bf16
    const float* __restrict__ bias,          // [N] fp32
    const float* __restrict__ R, int ldr,    // fp32 residual
    float* __restrict__ Cf, int ldcf,
    __bf16* __restrict__ Cb, int ldcb)
{
  __shared__ __attribute__((aligned(16))) __bf16 As[2][128*64];
  __shared__ __attribute__((aligned(16))) __bf16 Bs[2][64*64];
  int tid = threadIdx.x;
  int wave = tid>>6, lane = tid&63;
  int row0 = blockIdx.y*128, col0 = blockIdx.x*64;
  int wr = (wave>>1)*64, wc = (wave&1)*32;
  int lr = lane&15;
  f32x4 acc[4][2] = {};
  int NT = K >> 6;

  // stage tile at k0 into buffer b: LDS linear, source pre-swizzled (chunk c' holds logical c'^(r&7))
  auto stage = [&](int b, int k0){
    #pragma unroll
    for (int p=0;p<4;p++){
      int q = wave*256 + p*64 + lane;          // A chunk id 0..1023
      int r = q>>3, cl = (q&7)^(r&7);
      GLDS16(A + (size_t)(row0+r)*lda + k0 + cl*8, &As[b][(wave*256 + p*64)*8]);
    }
    #pragma unroll
    for (int p=0;p<2;p++){
      int q = wave*128 + p*64 + lane;          // B chunk id 0..511
      int r = q>>3, cl = (q&7)^(r&7);
      GLDS16(Bt + (size_t)(col0+r)*K + k0 + cl*8, &Bs[b][(wave*128 + p*64)*8]);
    }
  };

  stage(0, 0);
  for (int t=0; t<NT; t++){
    __syncthreads();                           // drains stage(t) (vmcnt0) + protects buffer reuse
    if (t+1 < NT) stage((t+1)&1, (t+1)<<6);    // issue next tile's loads (other buffer)
    int b = t&1;
    #pragma unroll
    for (int ks=0;ks<2;ks++){
      int c = ks*4 + (lane>>4);                // logical chunk = kk>>3
      bf16x8 af[4], bg[2];
      #pragma unroll
      for (int m=0;m<4;m++){
        int rowA = wr + m*16 + lr;
        af[m] = *(const bf16x8*)&As[b][rowA*64 + ((c ^ (rowA&7))<<3)];
      }
      #pragma unroll
      for (int n=0;n<2;n++){
        int rowB = wc + n*16 + lr;
        bg[n] = *(const bf16x8*)&Bs[b][rowB*64 + ((c ^ (rowB&7))<<3)];
      }
      #pragma unroll
      for (int m=0;m<4;m++)
        #pragma unroll
        for (int n=0;n<2;n++)
          acc[m][n] = __builtin_amdgcn_mfma_f32_16x16x32_bf16(af[m], bg[n], acc[m][n], 0,0,0);
    }
  }
  int rq = (lane>>4)*4;  // verified C/D layout: col = lane&15, row = (lane>>4)*4 + q
  #pragma unroll
  for (int m=0;m<4;m++){
    #pragma unroll
    for (int n=0;n<2;n++){
      int cc = col0 + wc + n*16 + lr;
      float bv = bias[cc];
      #pragma unroll
      for (int q=0;q<4;q++){
        int r = row0 + wr + m*16 + rq + q;
        float v = acc[m][n][q] + bv;
        if (RES)  v += R[(size_t)r*ldr + cc];
        if (GELU) v = gelu_f(v);
        if (OUTF) Cf[(size_t)r*ldcf + cc] = v;
        if (OUTB) Cb[(size_t)r*ldcb + cc] = (__bf16)v;
      }
    }
  }
}

// ---------------- batched LayerNorm -> fp32 + bf16, optional fused mu/phi ----------------
template<bool MUPHI>
__global__ __launch_bounds__(256) void k_ln(const float* __restrict__ Y, int ldy,
    float* __restrict__ Xo, int ldx, __bf16* __restrict__ Xb, int ldxb,
    const float* __restrict__ g, const float* __restrict__ b,
    const float* __restrict__ muw, const float* __restrict__ mub,
    const float* __restrict__ phiw, const float* __restrict__ phib,
    float* __restrict__ muA, float* __restrict__ phiA)
{
  int t = blockIdx.x;
  __shared__ float red[16];
  float y[4]; float s=0.f, s2=0.f;
  #pragma unroll
  for (int q=0;q<4;q++){
    y[q] = Y[(size_t)t*ldy + threadIdx.x + 256*q];
    s += y[q]; s2 += y[q]*y[q];
  }
  for (int o=32;o>0;o>>=1){ s += __shfl_down(s,o); s2 += __shfl_down(s2,o); }
  int wid = threadIdx.x>>6, lane = threadIdx.x&63;
  if (lane==0){ red[wid]=s; red[wid+8]=s2; }
  __syncthreads();
  if (threadIdx.x==0){
    float a=0.f,c=0.f;
    for (int w=0;w<4;w++){ a+=red[w]; c+=red[w+8]; }
    red[0]=a; red[8]=c;
  }
  __syncthreads();
  float mean = red[0]*(1.0f/MDIM);
  float var  = red[8]*(1.0f/MDIM) - mean*mean;
  float rs = rsqrtf(var + 1e-5f);
  float sm = 0.f, sp = 0.f;
  #pragma unroll
  for (int q=0;q<4;q++){
    int j = threadIdx.x + 256*q;
    float v = g[j]*(y[q]-mean)*rs + b[j];
    Xo[(size_t)t*ldx + j] = v;
    Xb[(size_t)t*ldxb + j] = (__bf16)v;
    if (MUPHI){ sm = fmaf(v, muw[j], sm); sp = fmaf(v, phiw[j], sp); }
  }
  if (MUPHI){
    for (int o=32;o>0;o>>=1){ sm+=__shfl_down(sm,o); sp+=__shfl_down(sp,o); }
    __syncthreads();
    if (lane==0){ red[wid]=sm; red[wid+8]=sp; }
    __syncthreads();
    if (threadIdx.x==0){
      float a=0.f,c=0.f;
      for (int w=0;w<4;w++){ a+=red[w]; c+=red[w+8]; }
      muA[t]  = sigmoid_f(a + mub[0]);
      phiA[t] = softplus_f(c + phib[0]) + 2.0f;
    }
  }
}

// ---------------- z0 = gelu(ZP + prev*wlast) -> Z fp32 + Zb bf16 (all rows) ----------------
__global__ void k_z0(const float* __restrict__ ZP, const float* __restrict__ wlast,
                     const float* __restrict__ prevg,
                     float* __restrict__ Z, __bf16* __restrict__ Zb){
  int t = blockIdx.y; int j = blockIdx.x*256 + threadIdx.x;
  float v = gelu_f(ZP[(size_t)t*MDIM + j] + prevg[t]*wlast[j]);
  Z[(size_t)t*MDIM + j] = v;
  Zb[(size_t)t*MDIM + j] = (__bf16)v;
}

// ================= dirty-row refinement stages =================

// fused z0 + fc1 (head block 0) for dirty rows
__global__ __launch_bounds__(256) void k_fc1z_dirty(
    const float* __restrict__ ZP, const float* __restrict__ wlast,
    const float* __restrict__ prevg,
    const __bf16* __restrict__ Wt, const float* __restrict__ bias,
    const int* __restrict__ dlist, const int* __restrict__ dcnt,
    float* __restrict__ Z, __bf16* __restrict__ Zb, __bf16* __restrict__ Ob)
{
  __shared__ __bf16 zl[MDIM];
  int nd = *dcnt;
  int jb = blockIdx.x;
  int j = jb*256 + threadIdx.x;
  for (int rs = blockIdx.y; rs < nd; rs += RST){
    int t = dlist[rs];
    float prev = prevg[t];
    #pragma unroll
    for (int q=0;q<4;q++){
      int k = threadIdx.x + 256*q;
      float v = gelu_f(ZP[(size_t)t*MDIM + k] + prev*wlast[k]);
      zl[k] = (__bf16)v;
      if (jb==0){ Z[(size_t)t*MDIM + k] = v; Zb[(size_t)t*MDIM + k] = (__bf16)v; }
    }
    __syncthreads();
    const __bf16* w = Wt + (size_t)j*MDIM;
    float acc = 0.f;
    for (int k=0;k<MDIM;k+=8){
      bf16x8 wv = *(const bf16x8*)&w[k];
      bf16x8 iv = *(const bf16x8*)&zl[k];
      #pragma unroll
      for (int u=0;u<8;u++) acc = fmaf((float)wv[u], (float)iv[u], acc);
    }
    acc = gelu_f(acc + bias[j]);
    Ob[(size_t)t*MDIM + j] = (__bf16)acc;
    __syncthreads();
  }
}

// fc matvec for dirty rows
template<bool GELU, bool RES, bool OUTB>
__global__ __launch_bounds__(256) void k_fc_dirty(
    const __bf16* __restrict__ In, const __bf16* __restrict__ Wt,
    const float* __restrict__ bias, const float* __restrict__ Rz,
    const int* __restrict__ dlist, const int* __restrict__ dcnt,
    __bf16* __restrict__ Ob, float* __restrict__ Of)
{
  int nd = *dcnt;
  int j = blockIdx.x*256 + threadIdx.x;
  for (int rs = blockIdx.y; rs < nd; rs += RST){
    int t = dlist[rs];
    const __bf16* in = In + (size_t)t*MDIM;
    const __bf16* w  = Wt + (size_t)j*MDIM;
    float acc = 0.f;
    for (int k=0;k<MDIM;k+=8){
      bf16x8 wv = *(const bf16x8*)&w[k];
      bf16x8 iv = *(const bf16x8*)&in[k];
      #pragma unroll
      for (int u=0;u<8;u++) acc = fmaf((float)wv[u], (float)iv[u], acc);
    }
    acc += bias[j];
    if (RES)  acc += Rz[(size_t)t*MDIM + j];
    if (GELU) acc = gelu_f(acc);
    if (OUTB) Ob[(size_t)t*MDIM + j] = (__bf16)acc;
    else      Of[(size_t)t*MDIM + j] = acc;
  }
}

// LayerNorm for dirty rows; optional fused mu/phi on final block
template<bool MUPHI>
__global__ __launch_bounds__(256) void k_ln_dirty(
    const float* __restrict__ Y,
    const float* __restrict__ g, const float* __restrict__ b,
    const int* __restrict__ dlist, const int* __restrict__ dcnt,
    float* __restrict__ Z, __bf16* __restrict__ Zb,
    const float* __restrict__ muw, const float* __restrict__ mub,
    const float* __restrict__ phiw, const float* __restrict__ phib,
    float* __restrict__ muA, float* __restrict__ phiA)
{
  int nd = *dcnt;
  __shared__ float red[16];
  int wid = threadIdx.x>>6, lane = threadIdx.x&63;
  for (int rs = blockIdx.x; rs < nd; rs += RST){
    int t = dlist[rs];
    float y[4]; float s=0.f, s2=0.f;
    #pragma unroll
    for (int q=0;q<4;q++){
      y[q] = Y[(size_t)t*MDIM + threadIdx.x + 256*q];
      s += y[q]; s2 += y[q]*y[q];
    }
    for (int o=32;o>0;o>>=1){ s += __shfl_down(s,o); s2 += __shfl_down(s2,o); }
    if (lane==0){ red[wid]=s; red[wid+8]=s2; }
    __syncthreads();
    if (threadIdx.x==0){
      float a=0.f,c=0.f;
      for (int w=0;w<4;w++){ a+=red[w]; c+=red[w+8]; }
      red[0]=a; red[8]=c;
    }
    __syncthreads();
    float mean = red[0]*(1.0f/MDIM);
    float var  = red[8]*(1.0f/MDIM) - mean*mean;
    float rs2 = rsqrtf(var + 1e-5f);
    float sm=0.f, sp=0.f;
    #pragma unroll
    for (int q=0;q<4;q++){
      int j = threadIdx.x + 256*q;
      float v = g[j]*(y[q]-mean)*rs2 + b[j];
      Z[(size_t)t*MDIM + j] = v;
      Zb[(size_t)t*MDIM + j] = (__bf16)v;
      if (MUPHI){ sm = fmaf(v, muw[j], sm); sp = fmaf(v, phiw[j], sp); }
    }
    __syncthreads();
    if (MUPHI){
      for (int o=32;o>0;o>>=1){ sm+=__shfl_down(sm,o); sp+=__shfl_down(sp,o); }
      if (lane==0){ red[wid]=sm; red[wid+8]=sp; }
      __syncthreads();
      if (threadIdx.x==0){
        float a=0.f,c=0.f;
        for (int w=0;w<4;w++){ a+=red[w]; c+=red[w+8]; }
        muA[t]  = sigmoid_f(a + mub[0]);
        phiA[t] = softplus_f(c + phib[0]) + 2.0f;
      }
      __syncthreads();
    }
  }
}

// ---------------- segmented prefix-product scan + dirty detection + output ----------------
__global__ __launch_bounds__(1024) void k_scan(
    const float* __restrict__ muA, const float* __restrict__ phiA,
    const unsigned char* __restrict__ bmask,
    float* __restrict__ prevg, int* __restrict__ dlist, int* __restrict__ dcnt,
    float* __restrict__ out)
{
  if (*dcnt == 0) return;   // converged: nothing changed since last scan
  __shared__ float v[2][TSEQ];
  __shared__ unsigned char f[2][TSEQ];
  __shared__ int cnt;
  int tid = threadIdx.x;
  if (tid==0) cnt = 0;
  for (int i=tid;i<TSEQ;i+=1024){
    v[0][i] = 1.0f - muA[i];
    f[0][i] = (i==0) || (bmask[i] != 0);
  }
  __syncthreads();
  int src=0;
  for (int off=1; off<TSEQ; off<<=1){
    int dst = src^1;
    for (int i=tid;i<TSEQ;i+=1024){
      float vv = v[src][i]; unsigned char ff = f[src][i];
      if (i>=off && !ff){ vv *= v[src][i-off]; ff = f[src][i-off]; }
      v[dst][i]=vv; f[dst][i]=ff;
    }
    __syncthreads();
    src = dst;
  }
  for (int i=tid;i<TSEQ;i+=1024){
    float rf = 1.0f - v[src][i];
    float prev = (i==0) ? -1.0f : (1.0f - v[src][i-1]);
    out[i]        = rf;
    out[TSEQ+i]   = muA[i];
    out[2*TSEQ+i] = phiA[i];
    float old = prevg[i];
    prevg[i] = prev;
    if (fabsf(prev - old) > 1e-4f){
      int pos = atomicAdd(&cnt, 1);
      dlist[pos] = i;
    }
  }
  __syncthreads();
  if (tid==0) *dcnt = cnt;
}

extern "C" void kernel_launch(void* const* d_in, const int* in_sizes, int n_in,
                              void* d_out, int out_size, void* d_ws, size_t ws_size,
                              hipStream_t stream) {
  const float* mol       = (const float*)d_in[0];
  const float* ratios    = (const float*)d_in[1];
  const float* desc      = (const float*)d_in[2];
  const float* svvec     = (const float*)d_in[3];
  const unsigned char* bmask = (const unsigned char*)d_in[4];
  const float* sp_proj_w = (const float*)d_in[5];
  const float* sp_proj_b = (const float*)d_in[6];
  const float* sp_fc1_w  = (const float*)d_in[7];
  const float* sp_fc1_b  = (const float*)d_in[8];
  const float* sp_fc2_w  = (const float*)d_in[9];
  const float* sp_fc2_b  = (const float*)d_in[10];
  const float* sp_ln_g   = (const float*)d_in[11];
  const float* sp_ln_b   = (const float*)d_in[12];
  const float* desc_w    = (const float*)d_in[13];
  const float* desc_b    = (const float*)d_in[14];
  const float* bh_proj_w = (const float*)d_in[15];
  const float* bh_proj_b = (const float*)d_in[16];
  const float* bh_fc1_w  = (const float*)d_in[17];
  const float* bh_fc1_b  = (const float*)d_in[18];
  const float* bh_fc2_w  = (const float*)d_in[19];
  const float* bh_fc2_b  = (const float*)d_in[20];
  const float* bh_ln_g   = (const float*)d_in[21];
  const float* bh_ln_b   = (const float*)d_in[22];
  const float* mu_w      = (const float*)d_in[23];
  const float* mu_b      = (const float*)d_in[24];
  const float* phi_w     = (const float*)d_in[25];
  const float* phi_b     = (const float*)d_in[26];
  float* out = (float*)d_out;

  char* p = (char*)d_ws;
  auto alloc = [&](size_t bytes)->char*{ char* r = p; p += (bytes + 255) & ~(size_t)255; return r; };
  const size_t MM = (size_t)MDIM*MDIM;
  float*  X    = (float*)alloc((size_t)TSEQ*MDIM*4);     // fp32 activations (sp x, later head z)
  __bf16* Xb   = (__bf16*)alloc((size_t)TSEQ*XLDB*2);    // bf16 [sp|demb]; later reused as Zb
  float*  Y    = (float*)alloc((size_t)TSEQ*MDIM*4);     // fp32 pre-LN
  float*  ZP   = (float*)alloc((size_t)TSEQ*MDIM*4);     // persistent head pre-activation
  __bf16* Hb16 = (__bf16*)alloc((size_t)TSEQ*MDIM*2);
  __bf16* WALL = (__bf16*)alloc(12*MM*2);                // W1T|W2T|U1T|U2T (3 blocks each)
  __bf16* WpT  = (__bf16*)alloc((size_t)MDIM*XLDB*2);    // [1024][1088]
  float*  PART = (float*)alloc((size_t)16*NRED*4);
  float*  P    = (float*)alloc((size_t)NSOL*MDIM*4);
  float*  mp   = (float*)alloc(MDIM*4);
  float*  prevg= (float*)alloc(TSEQ*4);
  float*  muA  = (float*)alloc(TSEQ*4);
  float*  phiA = (float*)alloc(TSEQ*4);
  int*    dlist= (int*)alloc(TSEQ*4);
  int*    dcnt = (int*)alloc(256);
  __bf16* W1T = WALL, *W2T = WALL + 3*MM, *U1T = WALL + 6*MM, *U2T = WALL + 9*MM;
  float*  Z    = X;      // alias: X fp32 dead after sp chain
  __bf16* Zb   = Xb;     // alias: Xb dead after zpre GEMM

  k_init<<<dim3((TSEQ+255)/256),256,0,stream>>>(prevg, dlist, dcnt);
  // weight convert+transpose (once per launch)
  k_cvtT12<<<dim3(32,32,12),256,0,stream>>>(sp_fc1_w, sp_fc2_w, bh_fc1_w, bh_fc2_w, WALL);
  k_cvtT<<<dim3(32,34,1),256,0,stream>>>(bh_proj_w + MM, WpT, XLDB, MDIM);

  k_solvP<<<dim3(4,NSOL,16),256,0,stream>>>(svvec, sp_proj_w, PART);
  k_molpart<<<dim3(4,1,16),256,0,stream>>>(mol, bh_proj_w, PART);
  k_red<<<dim3(NRED/256),256,0,stream>>>(PART, bh_proj_b, P, mp);
  k_sp0<<<dim3(4,TSEQ),256,0,stream>>>(ratios, P, sp_proj_b, X, Xb);
  k_demb<<<dim3(TSEQ),64,0,stream>>>(desc, desc_w, desc_b, Xb);

  // sp residual chain (bf16 MFMA GEMMs)
  for (int i=0;i<NBLK;i++){
    k_mfma_gemm<true,false,false,true><<<dim3(16,16),256,0,stream>>>(
        Xb, XLDB, MDIM, W1T + i*MM, sp_fc1_b + i*MDIM, nullptr, 0,
        nullptr, 0, Hb16, MDIM);
    k_mfma_gemm<false,true,true,false><<<dim3(16,16),256,0,stream>>>(
        Hb16, MDIM, MDIM, W2T + i*MM, sp_fc2_b + i*MDIM, X, MDIM,
        Y, MDIM, nullptr, 0);
    k_ln<false><<<dim3(TSEQ),256,0,stream>>>(Y, MDIM, X, MDIM, Xb, XLDB,
        sp_ln_g + i*MDIM, sp_ln_b + i*MDIM,
        nullptr, nullptr, nullptr, nullptr, nullptr, nullptr);
  }
  // z_pre = [sp|demb] @ bh_proj_w[1024:2112] + (mol part incl. bias)
  k_mfma_gemm<false,false,true,false><<<dim3(16,16),256,0,stream>>>(
      Xb, XLDB, XLDB, WpT, mp, nullptr, 0, ZP, MDIM, nullptr, 0);

  const float* wlast = bh_proj_w + (size_t)2112*MDIM;
  // ---- iteration 1: batched head with speculative prev ----
  k_z0<<<dim3(4,TSEQ),256,0,stream>>>(ZP, wlast, prevg, Z, Zb);
  for (int i=0;i<NBLK;i++){
    k_mfma_gemm<true,false,false,true><<<dim3(16,16),256,0,stream>>>(
        Zb, MDIM, MDIM, U1T + i*MM, bh_fc1_b + i*MDIM, nullptr, 0,
        nullptr, 0, Hb16, MDIM);
    k_mfma_gemm<false,true,true,false><<<dim3(16,16),256,0,stream>>>(
        Hb16, MDIM, MDIM, U2T + i*MM, bh_fc2_b + i*MDIM, Z, MDIM,
        Y, MDIM, nullptr, 0);
    if (i < NBLK-1)
      k_ln<false><<<dim3(TSEQ),256,0,stream>>>(Y, MDIM, Z, MDIM, Zb, MDIM,
          bh_ln_g + i*MDIM, bh_ln_b + i*MDIM,
          nullptr, nullptr, nullptr, nullptr, nullptr, nullptr);
    else
      k_ln<true><<<dim3(TSEQ),256,0,stream>>>(Y, MDIM, Z, MDIM, Zb, MDIM,
          bh_ln_g + i*MDIM, bh_ln_b + i*MDIM,
          mu_w, mu_b, phi_w, phi_b, muA, phiA);
  }
  k_scan<<<dim3(1),1024,0,stream>>>(muA, phiA, bmask, prevg, dlist, dcnt, out);

  // ---- refinement iterations: staged dirty-row head ----
  for (int it=1; it<KITER; it++){
    k_fc1z_dirty<<<dim3(4,RST),256,0,stream>>>(ZP, wlast, prevg,
        U1T, bh_fc1_b, dlist, dcnt, Z, Zb, Hb16);
    k_fc_dirty<false,true,false><<<dim3(4,RST),256,0,stream>>>(
        Hb16, U2T, bh_fc2_b, Z, dlist, dcnt, nullptr, Y);
    k_ln_dirty<false><<<dim3(RST),256,0,stream>>>(Y, bh_ln_g, bh_ln_b,
        dlist, dcnt, Z, Zb, nullptr, nullptr, nullptr, nullptr, nullptr, nullptr);
    for (int i=1;i<NBLK;i++){
      k_fc_dirty<true,false,true><<<dim3(4,RST),256,0,stream>>>(
          Zb, U1T + i*MM, bh_fc1_b + i*MDIM, nullptr, dlist, dcnt, Hb16, nullptr);
      k_fc_dirty<false,true,false><<<dim3(4,RST),256,0,stream>>>(
          Hb16, U2T + i*MM, bh_fc2_b + i*MDIM, Z, dlist, dcnt, nullptr, Y);
      if (i < NBLK-1)
        k_ln_dirty<false><<<dim3(RST),256,0,stream>>>(Y, bh_ln_g + i*MDIM, bh_ln_b + i*MDIM,
            dlist, dcnt, Z, Zb, nullptr, nullptr, nullptr, nullptr, nullptr, nullptr);
      else
        k_ln_dirty<true><<<dim3(RST),256,0,stream>>>(Y, bh_ln_g + i*MDIM, bh_ln_b + i*MDIM,
            dlist, dcnt, Z, Zb, mu_w, mu_b, phi_w, phi_b, muA, phiA);
    }
    k_scan<<<dim3(1),1024,0,stream>>>(muA, phiA, bmask, prevg, dlist, dcnt, out);
  }
  (void)in_sizes; (void)n_in; (void)out_size; (void)ws_size;
}